// Round 4
// baseline (254.368 us; speedup 1.0000x reference)
//
#include <hip/hip_runtime.h>
#include <math.h>

#define BB 32768
#define DD 512
#define CC 527
#define NCOLP 576   // padded W cols in Wbf (layout unchanged; only 33 tiles read)
#define BM 32       // rows per block
#define ZSH 544     // LDS z row stride (bf16/u16): 1088 B, 16B-aligned
#define XST 520     // LDS x row stride (bf16)

typedef __attribute__((ext_vector_type(8))) short bf16x8;
typedef __attribute__((ext_vector_type(4))) short bf16x4;
typedef __attribute__((ext_vector_type(4))) float f32x4;
typedef __attribute__((ext_vector_type(4))) unsigned int u32x4;
typedef f32x4 f32x4u __attribute__((aligned(4)));   // y rows only 4B-aligned (527 odd)

#define TJ4(OP) OP(0) OP(1) OP(2) OP(3)
#define C4(OP)  OP(0) OP(1) OP(2) OP(3)

#if __has_builtin(__builtin_amdgcn_exp2f)
#define EXP2F(v) __builtin_amdgcn_exp2f(v)
#else
#define EXP2F(v) exp2f(v)
#endif
#if __has_builtin(__builtin_amdgcn_logf)
#define LOG2F(v) __builtin_amdgcn_logf(v)
#else
#define LOG2F(v) __log2f(v)
#endif

__device__ __forceinline__ short f2bf(float f) {  // fp32 -> bf16 RNE
  unsigned u = __float_as_uint(f);
  u += 0x7fffu + ((u >> 16) & 1u);
  return (short)(u >> 16);
}
__device__ __forceinline__ bf16x8 pack8(f32x4 a, f32x4 b) {
  bf16x8 v;
  v[0]=f2bf(a.x); v[1]=f2bf(a.y); v[2]=f2bf(a.z); v[3]=f2bf(a.w);
  v[4]=f2bf(b.x); v[5]=f2bf(b.y); v[6]=f2bf(b.z); v[7]=f2bf(b.w);
  return v;
}

// 16-lane (DPP row) reductions: 4 x row_ror, pure VALU, no LDS pipe.
__device__ __forceinline__ int dppadd16(int v) {
  v += __builtin_amdgcn_update_dpp(0, v, 0x121, 0xf, 0xf, false);
  v += __builtin_amdgcn_update_dpp(0, v, 0x122, 0xf, 0xf, false);
  v += __builtin_amdgcn_update_dpp(0, v, 0x124, 0xf, 0xf, false);
  v += __builtin_amdgcn_update_dpp(0, v, 0x128, 0xf, 0xf, false);
  return v;
}
__device__ __forceinline__ int dppmax16i(int v) {
  int t;
  t = __builtin_amdgcn_update_dpp(0, v, 0x121, 0xf, 0xf, false); v = v > t ? v : t;
  t = __builtin_amdgcn_update_dpp(0, v, 0x122, 0xf, 0xf, false); v = v > t ? v : t;
  t = __builtin_amdgcn_update_dpp(0, v, 0x124, 0xf, 0xf, false); v = v > t ? v : t;
  t = __builtin_amdgcn_update_dpp(0, v, 0x128, 0xf, 0xf, false); v = v > t ? v : t;
  return v;
}

// bf16 bits -> order-preserving u16, then (mono<<10)|col: strict total order,
// no ties -> integer bisection always terminates on exact count match.
#define KEYOF(b, idx) ((int)(((((unsigned)(b)) ^ (0x8000u | (0xFFFFu * (((unsigned)(b)) >> 15)))) << 10) | (unsigned)(idx)))

// Block = 512 thr = 8 waves, 4 blocks/CU (LDS 34.9 KB). Prologue: x tile -> LDS
// bf16. GEMM: wave = 2 rowsets x 4-5 col-tiles (33 tiles cover C=527), B frag
// feeds 2 MFMAs, A from LDS. z stored to LDS as bf16 (+bias, RNE) -> halves the
// LDS tile vs f32 => 2x resident blocks for latency hiding. Epilogue: one row
// per 16-lane group; loss from dequantized bf16 z; top-k via integer-key
// bisection (key = mono-bf16<<10 | col, tie-free) with DPP-only reductions.
template<bool PRE>
__global__ __launch_bounds__(512, 8)
void fused_mfma_bce_topk(const float* __restrict__ x, const float* __restrict__ y,
                         const float* __restrict__ W, const short* __restrict__ Wbf,
                         const float* __restrict__ bias, const float* __restrict__ pw,
                         float* __restrict__ accum) {
  __shared__ __attribute__((aligned(16))) unsigned short zs_h[BM][ZSH]; // 34,816 B
  __shared__ float redL[8], redS[8];

  const int tid  = threadIdx.x;
  const int w    = tid >> 6, lane = tid & 63;
  const int cl   = lane & 15, quad = lane >> 4;
  const int row0 = blockIdx.x * BM;

  // ---------------- x -> LDS as bf16 (coalesced) ----------------
  unsigned short* xs = &zs_h[0][0];   // [BM][XST] bf16 stage, 33,280 B (unions)
  {
    const float* xblk = x + (size_t)row0 * DD;
#pragma unroll
    for (int i = 0; i < 8; ++i) {
      const int e = i * 2048 + tid * 4;        // f32 element index in 32x512 tile
      f32x4 v = *(const f32x4*)(xblk + e);
      const int r = e >> 9, c = e & 511;
      bf16x4 bv;
      bv[0] = f2bf(v.x); bv[1] = f2bf(v.y); bv[2] = f2bf(v.z); bv[3] = f2bf(v.w);
      *(bf16x4*)(xs + r * XST + c) = bv;       // ds_write_b64
    }
  }
  __syncthreads();

  // tile ranges: wave 0 -> [0,5), wave w>=1 -> [4w+1, 4w+5); 33 tiles total
  const int t0  = (w == 0) ? 0 : 4 * w + 1;
  const bool nt5 = (w == 0);

#define DECL(j) f32x4 P##j = (f32x4){0.f,0.f,0.f,0.f}; f32x4 Q##j = (f32x4){0.f,0.f,0.f,0.f};
  TJ4(DECL) DECL(4)
#undef DECL

  // ---------------- MFMA GEMM over K = 512 (A from LDS) ----------------
  const unsigned short* xr0 = xs + (size_t)cl * XST + quad * 8;          // rowset 0
  const unsigned short* xr1 = xs + (size_t)(16 + cl) * XST + quad * 8;   // rowset 1

  if (PRE) {
#define WB(j) const short* wb##j = Wbf + (size_t)((t0 + (j)) * 16 + cl) * DD + quad * 8;
    TJ4(WB) WB(4)
#undef WB
#define GSTEP(j) { \
    bf16x8 bfr = *(const bf16x8*)(wb##j + k0); \
    P##j = __builtin_amdgcn_mfma_f32_16x16x32_bf16(a0, bfr, P##j, 0, 0, 0); \
    Q##j = __builtin_amdgcn_mfma_f32_16x16x32_bf16(a1, bfr, Q##j, 0, 0, 0); }
    for (int k0 = 0; k0 < DD; k0 += 32) {
      bf16x8 a0 = *(const bf16x8*)(xr0 + k0);
      bf16x8 a1 = *(const bf16x8*)(xr1 + k0);
      TJ4(GSTEP)
      if (nt5) { GSTEP(4) }
    }
#undef GSTEP
  } else {
#define GSTEPF(j) { \
    int col = (t0 + (j)) * 16 + cl; \
    bf16x8 bfr = {0,0,0,0,0,0,0,0}; \
    if (col < CC) { \
      const float* wp = W + (size_t)col * DD + k0 + quad * 8; \
      bfr = pack8(*(const f32x4*)wp, *(const f32x4*)(wp + 4)); \
    } \
    P##j = __builtin_amdgcn_mfma_f32_16x16x32_bf16(a0, bfr, P##j, 0, 0, 0); \
    Q##j = __builtin_amdgcn_mfma_f32_16x16x32_bf16(a1, bfr, Q##j, 0, 0, 0); }
    for (int k0 = 0; k0 < DD; k0 += 32) {
      bf16x8 a0 = *(const bf16x8*)(xr0 + k0);
      bf16x8 a1 = *(const bf16x8*)(xr1 + k0);
      TJ4(GSTEPF)
      if (nt5) { GSTEPF(4) }
    }
#undef GSTEPF
  }

  // bias per owned tile (global, overlaps the pre-z-write barrier drain)
#define LB(j) float bt##j = 0.f; { int col = (t0 + (j)) * 16 + cl; if (col < CC) bt##j = bias[col]; }
  TJ4(LB)
  float bt4 = 0.f;
  if (nt5) { int col = 4 * 16 + cl; bt4 = bias[col]; }
#undef LB

  // all A-reads done before zs_h overwrites the x-stage region
  __syncthreads();

  // ---------------- z (+bias) -> LDS as bf16 ----------------
  // C/D layout: col = (t0+j)*16 + cl (<= 527 < ZSH), rows quad*4+r / 16+quad*4+r
#define WRZ(j) { \
    const int col = (t0 + (j)) * 16 + cl; \
    const int rr0 = quad * 4; \
    zs_h[rr0 + 0][col] = (unsigned short)f2bf(P##j[0] + bt##j); \
    zs_h[rr0 + 1][col] = (unsigned short)f2bf(P##j[1] + bt##j); \
    zs_h[rr0 + 2][col] = (unsigned short)f2bf(P##j[2] + bt##j); \
    zs_h[rr0 + 3][col] = (unsigned short)f2bf(P##j[3] + bt##j); \
    zs_h[16 + rr0 + 0][col] = (unsigned short)f2bf(Q##j[0] + bt##j); \
    zs_h[16 + rr0 + 1][col] = (unsigned short)f2bf(Q##j[1] + bt##j); \
    zs_h[16 + rr0 + 2][col] = (unsigned short)f2bf(Q##j[2] + bt##j); \
    zs_h[16 + rr0 + 3][col] = (unsigned short)f2bf(Q##j[3] + bt##j); }
  TJ4(WRZ)
  if (nt5) { WRZ(4) }
#undef WRZ

  __syncthreads();

  // ---------------- per-16-lane-group epilogue ----------------
  // group (w,quad) owns row erow; lane cl owns cols {128t+8cl..+7, t<4} + tail 512+cl
  const int erow = w * 4 + quad;                 // 0..31
  const float* yrow = y + (size_t)(row0 + erow) * CC;

#define KDECL(t) int K##t##_0, K##t##_1, K##t##_2, K##t##_3, K##t##_4, K##t##_5, K##t##_6, K##t##_7;
  C4(KDECL)
#undef KDECL
  int K32 = 0;
  unsigned ym0 = 0, ym1 = 0;
  float lossloc = 0.f;

  // loss + keys + positive-mask, one pass per chunk (8 cols/lane/chunk)
#define LE(t, e) { \
    unsigned b = (((e) & 1) ? (zr[(e) >> 1] >> 16) : (zr[(e) >> 1] & 0xFFFFu)); \
    float z = __uint_as_float(b << 16); \
    float yv = ((e) < 4) ? ya[(e)] : yb[(e) - 4]; \
    float pv = ((e) < 4) ? pa[(e)] : pb[(e) - 4]; \
    float l1 = LOG2F(1.f + EXP2F(fabsf(z) * -1.4426950408889634f)) * 0.6931471805599453f; \
    float sp = fmaxf(z, 0.f) + l1; \
    lossloc += pv * yv * (sp - z) + (1.f - yv) * sp; \
    if (yv > 0.5f) ym0 |= (1u << (8*(t)+(e))); \
    K##t##_##e = KEYOF(b, 128*(t) + 8*cl + (e)); }
#define LCH(t) { \
    u32x4 zr = *(const u32x4*)&zs_h[erow][128*(t) + 8*cl]; \
    f32x4 ya = (f32x4)(*(const f32x4u*)(yrow + 128*(t) + 8*cl)); \
    f32x4 yb = (f32x4)(*(const f32x4u*)(yrow + 128*(t) + 8*cl + 4)); \
    f32x4 pa = *(const f32x4*)(pw + 128*(t) + 8*cl); \
    f32x4 pb = *(const f32x4*)(pw + 128*(t) + 8*cl + 4); \
    LE(t,0) LE(t,1) LE(t,2) LE(t,3) LE(t,4) LE(t,5) LE(t,6) LE(t,7) }
  C4(LCH)
#undef LCH
#undef LE
  if (cl < 15) {              // tail cols 512..526
    const int col = 512 + cl;
    unsigned b = zs_h[erow][col];
    float z = __uint_as_float(b << 16);
    float yv = yrow[col];
    float pv = pw[col];
    float l1 = LOG2F(1.f + EXP2F(fabsf(z) * -1.4426950408889634f)) * 0.6931471805599453f;
    float sp = fmaxf(z, 0.f) + l1;
    lossloc += pv * yv * (sp - z) + (1.f - yv) * sp;
    if (yv > 0.5f) ym1 = 1u;
    K32 = KEYOF(b, col);
  }

  const int kk = dppadd16(__popc(ym0) + (int)ym1);

  // bracket: [-1, max-key]; integer bisection, exact count match guaranteed
  int mxK = K32;
#define MXK(t) { int m01 = K##t##_0 > K##t##_1 ? K##t##_0 : K##t##_1; \
    int m23 = K##t##_2 > K##t##_3 ? K##t##_2 : K##t##_3; \
    int m45 = K##t##_4 > K##t##_5 ? K##t##_4 : K##t##_5; \
    int m67 = K##t##_6 > K##t##_7 ? K##t##_6 : K##t##_7; \
    int ma = m01 > m23 ? m01 : m23; int mb = m45 > m67 ? m45 : m67; \
    int mc = ma > mb ? ma : mb; mxK = mxK > mc ? mxK : mc; }
  C4(MXK)
#undef MXK
  mxK = dppmax16i(mxK);

  int lo = -1, hi = mxK, th = 0;
  bool fnd = false;
#pragma unroll 1
  for (int it = 0; it < 32; ++it) {
    const int tm = (lo + hi) >> 1;
    int c = (K32 > tm);
#define CK(t) c += (K##t##_0 > tm) + (K##t##_1 > tm) + (K##t##_2 > tm) + (K##t##_3 > tm) \
             + (K##t##_4 > tm) + (K##t##_5 > tm) + (K##t##_6 > tm) + (K##t##_7 > tm);
    C4(CK)
#undef CK
    c = dppadd16(c);
    if (!fnd) {
      if (c == kk)                   { th = tm; fnd = true; }
      else if (tm <= lo || tm >= hi) { th = lo; fnd = true; }
      else if (c > kk)               lo = tm;
      else                           hi = tm;
    }
    if (__all(fnd)) break;
  }
  if (!fnd) th = lo;

  // hits among positives: decision = key > th
  int h = (int)(ym1 & (unsigned)(K32 > th));
#define HT(t) h += (int)((ym0 >> (8*(t)+0)) & 1u) & (int)(K##t##_0 > th); \
  h += (int)((ym0 >> (8*(t)+1)) & 1u) & (int)(K##t##_1 > th); \
  h += (int)((ym0 >> (8*(t)+2)) & 1u) & (int)(K##t##_2 > th); \
  h += (int)((ym0 >> (8*(t)+3)) & 1u) & (int)(K##t##_3 > th); \
  h += (int)((ym0 >> (8*(t)+4)) & 1u) & (int)(K##t##_4 > th); \
  h += (int)((ym0 >> (8*(t)+5)) & 1u) & (int)(K##t##_5 > th); \
  h += (int)((ym0 >> (8*(t)+6)) & 1u) & (int)(K##t##_6 > th); \
  h += (int)((ym0 >> (8*(t)+7)) & 1u) & (int)(K##t##_7 > th);
  C4(HT)
#undef HT
  h = dppadd16(h);

  float scoreloc = 0.f;
  if (cl == 0) {
    const int hv = h < kk ? h : kk;   // safety clamp
    scoreloc = (float)hv / (float)kk;
  }

  // loss+score: wave butterfly; block: LDS + one atomic per block per output
#pragma unroll
  for (int m = 1; m < 64; m <<= 1) {
    lossloc  += __shfl_xor(lossloc, m, 64);
    scoreloc += __shfl_xor(scoreloc, m, 64);
  }
  if (lane == 0) { redL[w] = lossloc; redS[w] = scoreloc; }
  __syncthreads();
  if (tid == 0) {
    float sl = 0.f, ss = 0.f;
#pragma unroll
    for (int i = 0; i < 8; ++i) { sl += redL[i]; ss += redS[i]; }
    atomicAdd(&accum[0], sl);
    atomicAdd(&accum[1], ss);
  }
}

__global__ void wcvt_kernel(const float* __restrict__ W, short* __restrict__ Wbf,
                            float* __restrict__ ws) {
  if (blockIdx.x == 0 && threadIdx.x == 0) { ws[0] = 0.f; ws[1] = 0.f; }
  int idx = (blockIdx.x * 256 + threadIdx.x) * 4;   // elem in [576*512]
  int row = idx >> 9;
  bf16x4 v = {0, 0, 0, 0};
  if (row < CC) {
    f32x4 f = *(const f32x4*)(W + idx);
    v[0]=f2bf(f.x); v[1]=f2bf(f.y); v[2]=f2bf(f.z); v[3]=f2bf(f.w);
  }
  *(bf16x4*)(Wbf + idx) = v;
}

__global__ void init_ws_kernel(float* ws) {
  ws[0] = 0.f;
  ws[1] = 0.f;
}

__global__ void finalize_kernel(const float* __restrict__ ws, float* __restrict__ out) {
  out[0] = (float)((double)ws[0] / ((double)BB * (double)CC));
  out[1] = (float)((double)ws[1] / (double)BB);
}

extern "C" void kernel_launch(void* const* d_in, const int* in_sizes, int n_in,
                              void* d_out, int out_size, void* d_ws, size_t ws_size,
                              hipStream_t stream) {
  const float* x  = (const float*)d_in[0];
  const float* y  = (const float*)d_in[1];
  const float* W  = (const float*)d_in[2];
  const float* b  = (const float*)d_in[3];
  const float* pw = (const float*)d_in[4];
  float* out = (float*)d_out;
  float* ws  = (float*)d_ws;
  short* Wbf = (short*)((char*)d_ws + 64);

  const size_t need = 64 + (size_t)NCOLP * DD * 2;
  const bool pre = (ws_size >= need);

  if (pre) {
    wcvt_kernel<<<dim3(NCOLP * DD / 1024), dim3(256), 0, stream>>>(W, Wbf, ws);
    fused_mfma_bce_topk<true><<<dim3(BB / BM), dim3(512), 0, stream>>>(
        x, y, W, Wbf, b, pw, ws);
  } else {
    init_ws_kernel<<<dim3(1), dim3(1), 0, stream>>>(ws);
    fused_mfma_bce_topk<false><<<dim3(BB / BM), dim3(512), 0, stream>>>(
        x, y, W, Wbf, b, pw, ws);
  }
  finalize_kernel<<<dim3(1), dim3(1), 0, stream>>>(ws, out);
}